// Round 2
// baseline (1110.570 us; speedup 1.0000x reference)
//
#include <hip/hip_runtime.h>

#define NUM_PAIRS 10

__global__ void zero_kernel(float* __restrict__ out, int n) {
    int i = blockIdx.x * blockDim.x + threadIdx.x;
    if (i < n) out[i] = 0.0f;
}

__global__ __launch_bounds__(256) void force_kernel(
    const float* __restrict__ raw_charges,
    const float* __restrict__ A,
    const float* __restrict__ rho,
    const float* __restrict__ C,
    const float* __restrict__ distances,
    const float* __restrict__ inv_d2_arr,
    const float* __restrict__ uv,            // [E,3]
    const int*   __restrict__ edge_src,      // edge_index row 0
    const int*   __restrict__ pair_indices,
    const int*   __restrict__ src_elem,
    const int*   __restrict__ tgt_elem,
    float* __restrict__ forces,              // [n_nodes,3]
    int n_edges)
{
    __shared__ float s_AoR[NUM_PAIRS];    // A/rho
    __shared__ float s_invRho[NUM_PAIRS]; // 1/rho
    __shared__ float s_C6[NUM_PAIRS];     // 6*C
    __shared__ float s_qq[16];            // q[s]*q[t]

    const int t = threadIdx.x;
    if (t < NUM_PAIRS) {
        float r = rho[t];
        float ir = 1.0f / r;
        s_invRho[t] = ir;
        s_AoR[t]    = A[t] * ir;
        s_C6[t]     = 6.0f * C[t];
    }
    if (t < 16) {
        float q0 = raw_charges[0];
        // charges: [Cd, Se, S, Zn] = [q0, -q0, raw[1], raw[2]]
        float qs0 = q0;
        float qs1 = -q0;
        float qs2 = raw_charges[1];
        float qs3 = raw_charges[2];
        float qa = (t & 3) == 0 ? qs0 : (t & 3) == 1 ? qs1 : (t & 3) == 2 ? qs2 : qs3;
        int hb = t >> 2;
        float qb = hb == 0 ? qs0 : hb == 1 ? qs1 : hb == 2 ? qs2 : qs3;
        s_qq[t] = qa * qb;
    }
    __syncthreads();

    int e = blockIdx.x * blockDim.x + t;
    if (e >= n_edges) return;

    float d      = distances[e];
    float inv_d2 = inv_d2_arr[e];
    int   p      = pair_indices[e];
    int   se     = src_elem[e];
    int   te     = tgt_elem[e];

    float inv_d  = inv_d2 * d;   // 1/d without a division
    float inv_d6 = inv_d2 * inv_d2 * inv_d2;

    float pot  = s_AoR[p] * __expf(-d * s_invRho[p]) - s_C6[p] * inv_d6 * inv_d;
    float coul = s_qq[(te << 2) | se] * inv_d2;   // product is symmetric in (s,t)
    float total = pot + coul;

    float ux = uv[3 * e + 0];
    float uy = uv[3 * e + 1];
    float uz = uv[3 * e + 2];

    int node = edge_src[e];
    float* dst = forces + 3 * node;
    // Native HW fp32 atomic (global_atomic_add_f32). Safe on coarse-grained
    // device memory (d_out is hipMalloc'd). Default atomicAdd emits a CAS
    // loop without -munsafe-fp-atomics — that was the 947us bottleneck.
    unsafeAtomicAdd(dst + 0, -total * ux);
    unsafeAtomicAdd(dst + 1, -total * uy);
    unsafeAtomicAdd(dst + 2, -total * uz);
}

extern "C" void kernel_launch(void* const* d_in, const int* in_sizes, int n_in,
                              void* d_out, int out_size, void* d_ws, size_t ws_size,
                              hipStream_t stream) {
    const float* raw_charges = (const float*)d_in[0];
    const float* A           = (const float*)d_in[1];
    const float* rho         = (const float*)d_in[2];
    const float* C           = (const float*)d_in[3];
    const float* distances   = (const float*)d_in[4];
    const float* inv_d2      = (const float*)d_in[5];
    const float* uv          = (const float*)d_in[6];
    const int*   edge_index  = (const int*)d_in[7];   // [2, E]
    const int*   pair_idx    = (const int*)d_in[8];
    const int*   src_elem    = (const int*)d_in[9];
    const int*   tgt_elem    = (const int*)d_in[10];

    float* forces = (float*)d_out;
    const int n_edges = in_sizes[4];
    const int n_out   = out_size;          // n_nodes * 3

    const int ZB = 256;
    zero_kernel<<<(n_out + ZB - 1) / ZB, ZB, 0, stream>>>(forces, n_out);

    const int B = 256;
    const int grid = (n_edges + B - 1) / B;
    force_kernel<<<grid, B, 0, stream>>>(raw_charges, A, rho, C,
                                         distances, inv_d2, uv,
                                         edge_index /* row 0 */, pair_idx,
                                         src_elem, tgt_elem,
                                         forces, n_edges);
}

// Round 3
// 1109.842 us; speedup vs baseline: 1.0007x; 1.0007x over previous
//
#include <hip/hip_runtime.h>

#define NUM_PAIRS 10
#define NCOPIES 8   // one accumulator copy per XCD

__device__ __forceinline__ unsigned xcc_id() {
    unsigned x;
    asm volatile("s_getreg_b32 %0, hwreg(HW_REG_XCC_ID)" : "=s"(x));
    return x & (NCOPIES - 1);
}

__global__ void zero_kernel(float4* __restrict__ p, int n4) {
    int i = blockIdx.x * blockDim.x + threadIdx.x;
    if (i < n4) p[i] = make_float4(0.f, 0.f, 0.f, 0.f);
}

__global__ void zero_kernel_f(float* __restrict__ p, int n) {
    int i = blockIdx.x * blockDim.x + threadIdx.x;
    if (i < n) p[i] = 0.0f;
}

template <bool PRIVATIZED>
__global__ __launch_bounds__(256) void force_kernel(
    const float* __restrict__ raw_charges,
    const float* __restrict__ A,
    const float* __restrict__ rho,
    const float* __restrict__ C,
    const float* __restrict__ distances,
    const float* __restrict__ inv_d2_arr,
    const float* __restrict__ uv,            // [E,3]
    const int*   __restrict__ edge_src,      // edge_index row 0
    const int*   __restrict__ pair_indices,
    const int*   __restrict__ src_elem,
    const int*   __restrict__ tgt_elem,
    float* __restrict__ acc,                 // PRIVATIZED ? ws[8][n_out] : forces[n_out]
    int n_edges, int n_out)
{
    __shared__ float s_AoR[NUM_PAIRS];    // A/rho
    __shared__ float s_invRho[NUM_PAIRS]; // 1/rho
    __shared__ float s_C6[NUM_PAIRS];     // 6*C
    __shared__ float s_qq[16];            // q[s]*q[t]

    const int t = threadIdx.x;
    if (t < NUM_PAIRS) {
        float r = rho[t];
        float ir = 1.0f / r;
        s_invRho[t] = ir;
        s_AoR[t]    = A[t] * ir;
        s_C6[t]     = 6.0f * C[t];
    }
    if (t < 16) {
        float q0 = raw_charges[0];
        // charges: [Cd, Se, S, Zn] = [q0, -q0, raw[1], raw[2]]
        float qs0 = q0, qs1 = -q0, qs2 = raw_charges[1], qs3 = raw_charges[2];
        float qa = (t & 3) == 0 ? qs0 : (t & 3) == 1 ? qs1 : (t & 3) == 2 ? qs2 : qs3;
        int hb = t >> 2;
        float qb = hb == 0 ? qs0 : hb == 1 ? qs1 : hb == 2 ? qs2 : qs3;
        s_qq[t] = qa * qb;
    }
    __syncthreads();

    // per-XCD private copy: workgroup-scope atomics execute in the local
    // XCD L2 (no sc1 bypass). All writers of copy[x] are physically on XCD x,
    // so L2-local atomicity is sufficient regardless of dispatch mapping.
    float* base = acc;
    if (PRIVATIZED) base += (size_t)xcc_id() * n_out;

    int e = blockIdx.x * blockDim.x + t;
    if (e >= n_edges) return;

    float d      = distances[e];
    float inv_d2 = inv_d2_arr[e];
    int   p      = pair_indices[e];
    int   se     = src_elem[e];
    int   te     = tgt_elem[e];

    float inv_d  = inv_d2 * d;   // 1/d without a division
    float inv_d6 = inv_d2 * inv_d2 * inv_d2;

    float pot  = s_AoR[p] * __expf(-d * s_invRho[p]) - s_C6[p] * inv_d6 * inv_d;
    float coul = s_qq[(te << 2) | se] * inv_d2;
    float total = pot + coul;

    float ux = uv[3 * e + 0];
    float uy = uv[3 * e + 1];
    float uz = uv[3 * e + 2];

    int node = edge_src[e];
    float* dst = base + 3 * node;
    if (PRIVATIZED) {
        __hip_atomic_fetch_add(dst + 0, -total * ux, __ATOMIC_RELAXED, __HIP_MEMORY_SCOPE_WORKGROUP);
        __hip_atomic_fetch_add(dst + 1, -total * uy, __ATOMIC_RELAXED, __HIP_MEMORY_SCOPE_WORKGROUP);
        __hip_atomic_fetch_add(dst + 2, -total * uz, __ATOMIC_RELAXED, __HIP_MEMORY_SCOPE_WORKGROUP);
    } else {
        unsafeAtomicAdd(dst + 0, -total * ux);
        unsafeAtomicAdd(dst + 1, -total * uy);
        unsafeAtomicAdd(dst + 2, -total * uz);
    }
}

__global__ __launch_bounds__(256) void reduce_kernel(
    const float4* __restrict__ ws, float4* __restrict__ out, int n4, int stride4)
{
    int i = blockIdx.x * blockDim.x + threadIdx.x;
    if (i >= n4) return;
    float4 s = make_float4(0.f, 0.f, 0.f, 0.f);
#pragma unroll
    for (int c = 0; c < NCOPIES; ++c) {
        float4 v = ws[(size_t)c * stride4 + i];
        s.x += v.x; s.y += v.y; s.z += v.z; s.w += v.w;
    }
    out[i] = s;
}

extern "C" void kernel_launch(void* const* d_in, const int* in_sizes, int n_in,
                              void* d_out, int out_size, void* d_ws, size_t ws_size,
                              hipStream_t stream) {
    const float* raw_charges = (const float*)d_in[0];
    const float* A           = (const float*)d_in[1];
    const float* rho         = (const float*)d_in[2];
    const float* C           = (const float*)d_in[3];
    const float* distances   = (const float*)d_in[4];
    const float* inv_d2      = (const float*)d_in[5];
    const float* uv          = (const float*)d_in[6];
    const int*   edge_index  = (const int*)d_in[7];   // [2, E]
    const int*   pair_idx    = (const int*)d_in[8];
    const int*   src_elem    = (const int*)d_in[9];
    const int*   tgt_elem    = (const int*)d_in[10];

    float* forces = (float*)d_out;
    const int n_edges = in_sizes[4];
    const int n_out   = out_size;          // n_nodes * 3 (= 300000, divisible by 4)

    const int B = 256;
    const int grid = (n_edges + B - 1) / B;
    const size_t need_ws = (size_t)NCOPIES * n_out * sizeof(float);

    if (ws_size >= need_ws && (n_out % 4) == 0) {
        float* ws = (float*)d_ws;
        int n4_ws = NCOPIES * n_out / 4;
        zero_kernel<<<(n4_ws + B - 1) / B, B, 0, stream>>>((float4*)ws, n4_ws);

        force_kernel<true><<<grid, B, 0, stream>>>(raw_charges, A, rho, C,
                                                   distances, inv_d2, uv,
                                                   edge_index, pair_idx,
                                                   src_elem, tgt_elem,
                                                   ws, n_edges, n_out);

        int n4 = n_out / 4;
        reduce_kernel<<<(n4 + B - 1) / B, B, 0, stream>>>((const float4*)ws,
                                                          (float4*)forces, n4, n4);
    } else {
        zero_kernel_f<<<(n_out + B - 1) / B, B, 0, stream>>>(forces, n_out);
        force_kernel<false><<<grid, B, 0, stream>>>(raw_charges, A, rho, C,
                                                    distances, inv_d2, uv,
                                                    edge_index, pair_idx,
                                                    src_elem, tgt_elem,
                                                    forces, n_edges, n_out);
    }
}

// Round 4
// 517.977 us; speedup vs baseline: 2.1441x; 2.1426x over previous
//
#include <hip/hip_runtime.h>
#include <math.h>

#define NUM_PAIRS 10
#define NB_SHIFT 7                 // 128 nodes per bucket
#define NODES_PER_BUCKET 128
#define MAX_NB 1024
#define EDGES_PER_BLOCK 4096       // 16 per thread at B=256

__global__ void zero_int_kernel(int* __restrict__ p, int n) {
    int i = blockIdx.x * blockDim.x + threadIdx.x;
    if (i < n) p[i] = 0;
}

__global__ void zero_kernel_f(float* __restrict__ p, int n) {
    int i = blockIdx.x * blockDim.x + threadIdx.x;
    if (i < n) p[i] = 0.0f;
}

__device__ __forceinline__ void load_params(
    int t,
    const float* __restrict__ raw_charges,
    const float* __restrict__ A,
    const float* __restrict__ rho,
    const float* __restrict__ C,
    float* s_AoR, float* s_invRho, float* s_C6, float* s_qq)
{
    if (t < NUM_PAIRS) {
        float r = rho[t];
        float ir = 1.0f / r;
        s_invRho[t] = ir;
        s_AoR[t]    = A[t] * ir;
        s_C6[t]     = 6.0f * C[t];
    }
    if (t < 16) {
        float q0 = raw_charges[0];
        // charges: [Cd, Se, S, Zn] = [q0, -q0, raw[1], raw[2]]
        float qs0 = q0, qs1 = -q0, qs2 = raw_charges[1], qs3 = raw_charges[2];
        float qa = (t & 3) == 0 ? qs0 : (t & 3) == 1 ? qs1 : (t & 3) == 2 ? qs2 : qs3;
        int hb = t >> 2;
        float qb = hb == 0 ? qs0 : hb == 1 ? qs1 : hb == 2 ? qs2 : qs3;
        s_qq[t] = qa * qb;
    }
}

__device__ __forceinline__ float edge_force(
    float d, float inv_d2, int p, int se, int te,
    const float* s_AoR, const float* s_invRho, const float* s_C6, const float* s_qq)
{
    float inv_d  = inv_d2 * d;                 // 1/d without a division
    float inv_d6 = inv_d2 * inv_d2 * inv_d2;
    float pot  = s_AoR[p] * __expf(-d * s_invRho[p]) - s_C6[p] * inv_d6 * inv_d;
    float coul = s_qq[(te << 2) | se] * inv_d2;
    return pot + coul;
}

// Phase A: compute per-edge force vectors and append them into node-range
// buckets in d_ws. Append = block-local LDS count -> one global int atomic
// per (block,bucket) to reserve a range -> LDS running counter for position.
__global__ __launch_bounds__(256) void bin_kernel(
    const float* __restrict__ raw_charges,
    const float* __restrict__ A,
    const float* __restrict__ rho,
    const float* __restrict__ C,
    const float* __restrict__ distances,
    const float* __restrict__ inv_d2_arr,
    const float* __restrict__ uv,            // [E,3]
    const int*   __restrict__ edge_src,      // edge_index row 0
    const int*   __restrict__ pair_indices,
    const int*   __restrict__ src_elem,
    const int*   __restrict__ tgt_elem,
    int*    __restrict__ g_cnt,              // [nb]
    float4* __restrict__ buf,                // [nb][cap]
    int cap, int n_edges, int nb)
{
    __shared__ int s_cnt[MAX_NB];
    __shared__ int s_base[MAX_NB];
    __shared__ float s_AoR[NUM_PAIRS], s_invRho[NUM_PAIRS], s_C6[NUM_PAIRS], s_qq[16];

    const int t = threadIdx.x;
    for (int k = t; k < nb; k += 256) s_cnt[k] = 0;
    load_params(t, raw_charges, A, rho, C, s_AoR, s_invRho, s_C6, s_qq);
    __syncthreads();

    const int base_e = blockIdx.x * EDGES_PER_BLOCK;

    // scan 1: count bucket occupancy for this block's edges
#pragma unroll
    for (int j = 0; j < EDGES_PER_BLOCK / 256; ++j) {
        int e = base_e + j * 256 + t;
        if (e < n_edges) {
            int b = edge_src[e] >> NB_SHIFT;
            atomicAdd(&s_cnt[b], 1);
        }
    }
    __syncthreads();

    // reserve contiguous ranges in each bucket
    for (int k = t; k < nb; k += 256) {
        int c = s_cnt[k];
        s_base[k] = c ? atomicAdd(&g_cnt[k], c) : 0;
        s_cnt[k] = 0;   // reuse as running position
    }
    __syncthreads();

    // scan 2: compute force vectors and write records
#pragma unroll
    for (int j = 0; j < EDGES_PER_BLOCK / 256; ++j) {
        int e = base_e + j * 256 + t;
        if (e >= n_edges) continue;
        float d      = distances[e];
        float inv_d2 = inv_d2_arr[e];
        int   p      = pair_indices[e];
        int   se     = src_elem[e];
        int   te     = tgt_elem[e];
        float total  = edge_force(d, inv_d2, p, se, te, s_AoR, s_invRho, s_C6, s_qq);

        float ux = uv[3 * e + 0];
        float uy = uv[3 * e + 1];
        float uz = uv[3 * e + 2];

        int node  = edge_src[e];
        int b     = node >> NB_SHIFT;
        int local = node & (NODES_PER_BUCKET - 1);
        int pos   = s_base[b] + atomicAdd(&s_cnt[b], 1);
        if (pos < cap)
            buf[(size_t)b * cap + pos] =
                make_float4(-total * ux, -total * uy, -total * uz, __int_as_float(local));
    }
}

// Phase B: one block per bucket; stream records coalesced, accumulate in LDS,
// write the bucket's 128 nodes out coalesced. Covers all nodes (zeroes too).
__global__ __launch_bounds__(256) void gather_kernel(
    const float4* __restrict__ buf,
    const int*    __restrict__ g_cnt,
    float* __restrict__ forces,
    int cap, int n_out)
{
    __shared__ float s_acc[NODES_PER_BUCKET * 3];
    const int b = blockIdx.x;
    const int t = threadIdx.x;

    for (int k = t; k < NODES_PER_BUCKET * 3; k += 256) s_acc[k] = 0.0f;
    __syncthreads();

    int cnt = g_cnt[b];
    if (cnt > cap) cnt = cap;
    const float4* p = buf + (size_t)b * cap;
    for (int i = t; i < cnt; i += 256) {
        float4 r = p[i];
        int local = __float_as_int(r.w);
        atomicAdd(&s_acc[local * 3 + 0], r.x);
        atomicAdd(&s_acc[local * 3 + 1], r.y);
        atomicAdd(&s_acc[local * 3 + 2], r.z);
    }
    __syncthreads();

    int base = b * NODES_PER_BUCKET * 3;
    for (int k = t; k < NODES_PER_BUCKET * 3; k += 256) {
        int o = base + k;
        if (o < n_out) forces[o] = s_acc[k];
    }
}

// Fallback: direct scatter with native fp32 atomics (round-2 path).
__global__ __launch_bounds__(256) void force_kernel_direct(
    const float* __restrict__ raw_charges,
    const float* __restrict__ A,
    const float* __restrict__ rho,
    const float* __restrict__ C,
    const float* __restrict__ distances,
    const float* __restrict__ inv_d2_arr,
    const float* __restrict__ uv,
    const int*   __restrict__ edge_src,
    const int*   __restrict__ pair_indices,
    const int*   __restrict__ src_elem,
    const int*   __restrict__ tgt_elem,
    float* __restrict__ forces,
    int n_edges)
{
    __shared__ float s_AoR[NUM_PAIRS], s_invRho[NUM_PAIRS], s_C6[NUM_PAIRS], s_qq[16];
    const int t = threadIdx.x;
    load_params(t, raw_charges, A, rho, C, s_AoR, s_invRho, s_C6, s_qq);
    __syncthreads();

    int e = blockIdx.x * blockDim.x + t;
    if (e >= n_edges) return;
    float total = edge_force(distances[e], inv_d2_arr[e], pair_indices[e],
                             src_elem[e], tgt_elem[e], s_AoR, s_invRho, s_C6, s_qq);
    float ux = uv[3 * e + 0], uy = uv[3 * e + 1], uz = uv[3 * e + 2];
    float* dst = forces + 3 * edge_src[e];
    unsafeAtomicAdd(dst + 0, -total * ux);
    unsafeAtomicAdd(dst + 1, -total * uy);
    unsafeAtomicAdd(dst + 2, -total * uz);
}

extern "C" void kernel_launch(void* const* d_in, const int* in_sizes, int n_in,
                              void* d_out, int out_size, void* d_ws, size_t ws_size,
                              hipStream_t stream) {
    const float* raw_charges = (const float*)d_in[0];
    const float* A           = (const float*)d_in[1];
    const float* rho         = (const float*)d_in[2];
    const float* C           = (const float*)d_in[3];
    const float* distances   = (const float*)d_in[4];
    const float* inv_d2      = (const float*)d_in[5];
    const float* uv          = (const float*)d_in[6];
    const int*   edge_index  = (const int*)d_in[7];   // [2, E]; row 0 = source
    const int*   pair_idx    = (const int*)d_in[8];
    const int*   src_elem    = (const int*)d_in[9];
    const int*   tgt_elem    = (const int*)d_in[10];

    float* forces = (float*)d_out;
    const int n_edges = in_sizes[4];
    const int n_out   = out_size;            // n_nodes * 3
    const int n_nodes = n_out / 3;

    const int B = 256;
    const int nb = (n_nodes + NODES_PER_BUCKET - 1) >> NB_SHIFT;
    const long mean = (long)n_edges / (nb > 0 ? nb : 1);
    int cap = (int)((mean + 10.0 * sqrt((double)mean) + 255.0));
    cap = (cap + 255) & ~255;

    const size_t hdr = 8192;   // g_cnt region (nb ints, padded/aligned)
    const size_t need = hdr + (size_t)nb * (size_t)cap * sizeof(float4);

    if (nb <= MAX_NB && ws_size >= need) {
        int*    g_cnt = (int*)d_ws;
        float4* buf   = (float4*)((char*)d_ws + hdr);

        zero_int_kernel<<<(nb + B - 1) / B, B, 0, stream>>>(g_cnt, nb);

        int gridA = (n_edges + EDGES_PER_BLOCK - 1) / EDGES_PER_BLOCK;
        bin_kernel<<<gridA, B, 0, stream>>>(raw_charges, A, rho, C,
                                            distances, inv_d2, uv,
                                            edge_index, pair_idx, src_elem, tgt_elem,
                                            g_cnt, buf, cap, n_edges, nb);

        gather_kernel<<<nb, B, 0, stream>>>(buf, g_cnt, forces, cap, n_out);
    } else {
        zero_kernel_f<<<(n_out + B - 1) / B, B, 0, stream>>>(forces, n_out);
        int grid = (n_edges + B - 1) / B;
        force_kernel_direct<<<grid, B, 0, stream>>>(raw_charges, A, rho, C,
                                                    distances, inv_d2, uv,
                                                    edge_index, pair_idx,
                                                    src_elem, tgt_elem,
                                                    forces, n_edges);
    }
}

// Round 5
// 498.971 us; speedup vs baseline: 2.2257x; 1.0381x over previous
//
#include <hip/hip_runtime.h>
#include <math.h>

#define NUM_PAIRS 10
#define NB_SHIFT 7                 // 128 nodes per bucket
#define NODES_PER_BUCKET 128
#define MAX_NB 1024
#define EDGES_PER_BLOCK 4096       // 256 threads * 4 edges * 4 chunks
#define CHUNK 1024                 // 256 threads * 4 edges

__global__ void zero_int_kernel(int* __restrict__ p, int n) {
    int i = blockIdx.x * blockDim.x + threadIdx.x;
    if (i < n) p[i] = 0;
}

__global__ void zero_kernel_f(float* __restrict__ p, int n) {
    int i = blockIdx.x * blockDim.x + threadIdx.x;
    if (i < n) p[i] = 0.0f;
}

__device__ __forceinline__ void load_params(
    int t,
    const float* __restrict__ raw_charges,
    const float* __restrict__ A,
    const float* __restrict__ rho,
    const float* __restrict__ C,
    float* s_AoR, float* s_invRho, float* s_C6, float* s_qq)
{
    if (t < NUM_PAIRS) {
        float r = rho[t];
        float ir = 1.0f / r;
        s_invRho[t] = ir;
        s_AoR[t]    = A[t] * ir;
        s_C6[t]     = 6.0f * C[t];
    }
    if (t < 16) {
        float q0 = raw_charges[0];
        // charges: [Cd, Se, S, Zn] = [q0, -q0, raw[1], raw[2]]
        float qs0 = q0, qs1 = -q0, qs2 = raw_charges[1], qs3 = raw_charges[2];
        float qa = (t & 3) == 0 ? qs0 : (t & 3) == 1 ? qs1 : (t & 3) == 2 ? qs2 : qs3;
        int hb = t >> 2;
        float qb = hb == 0 ? qs0 : hb == 1 ? qs1 : hb == 2 ? qs2 : qs3;
        s_qq[t] = qa * qb;
    }
}

__device__ __forceinline__ float edge_force(
    float d, float inv_d2, int p, int se, int te,
    const float* s_AoR, const float* s_invRho, const float* s_C6, const float* s_qq)
{
    float inv_d  = inv_d2 * d;                 // 1/d without a division
    float inv_d6 = inv_d2 * inv_d2 * inv_d2;
    float pot  = s_AoR[p] * __expf(-d * s_invRho[p]) - s_C6[p] * inv_d6 * inv_d;
    float coul = s_qq[(te << 2) | se] * inv_d2;
    return pot + coul;
}

// Phase A: per-edge force vectors appended into node-range buckets in d_ws.
// MLP-oriented: each thread owns 4 consecutive edges per chunk; all inputs
// loaded as independent 16B vector loads; edge_src read once into registers.
__global__ __launch_bounds__(256) void bin_kernel(
    const float* __restrict__ raw_charges,
    const float* __restrict__ A,
    const float* __restrict__ rho,
    const float* __restrict__ C,
    const float* __restrict__ distances,
    const float* __restrict__ inv_d2_arr,
    const float* __restrict__ uv,            // [E,3]
    const int*   __restrict__ edge_src,      // edge_index row 0
    const int*   __restrict__ pair_indices,
    const int*   __restrict__ src_elem,
    const int*   __restrict__ tgt_elem,
    int*    __restrict__ g_cnt,              // [nb]
    float4* __restrict__ buf,                // [nb][cap]
    int cap, int n_edges, int nb)
{
    __shared__ int s_cnt[MAX_NB];
    __shared__ int s_base[MAX_NB];
    __shared__ float s_AoR[NUM_PAIRS], s_invRho[NUM_PAIRS], s_C6[NUM_PAIRS], s_qq[16];

    const int t = threadIdx.x;
    for (int k = t; k < nb; k += 256) s_cnt[k] = 0;
    load_params(t, raw_charges, A, rho, C, s_AoR, s_invRho, s_C6, s_qq);
    __syncthreads();

    const int blk_base = blockIdx.x * EDGES_PER_BLOCK;
    const bool full = (blk_base + EDGES_PER_BLOCK) <= n_edges;

    int4 src4[4];
    if (full) {
        // one coalesced int4 load per chunk, all 4 issued back-to-back
#pragma unroll
        for (int c = 0; c < 4; ++c)
            src4[c] = *(const int4*)(edge_src + blk_base + c * CHUNK + t * 4);
#pragma unroll
        for (int c = 0; c < 4; ++c) {
            atomicAdd(&s_cnt[src4[c].x >> NB_SHIFT], 1);
            atomicAdd(&s_cnt[src4[c].y >> NB_SHIFT], 1);
            atomicAdd(&s_cnt[src4[c].z >> NB_SHIFT], 1);
            atomicAdd(&s_cnt[src4[c].w >> NB_SHIFT], 1);
        }
    } else {
        for (int j = 0; j < EDGES_PER_BLOCK / 256; ++j) {
            int e = blk_base + j * 256 + t;
            if (e < n_edges) atomicAdd(&s_cnt[edge_src[e] >> NB_SHIFT], 1);
        }
    }
    __syncthreads();

    // reserve contiguous ranges in each bucket
    for (int k = t; k < nb; k += 256) {
        int c = s_cnt[k];
        s_base[k] = c ? atomicAdd(&g_cnt[k], c) : 0;
        s_cnt[k] = 0;   // reuse as running position
    }
    __syncthreads();

    if (full) {
#pragma unroll
        for (int c = 0; c < 4; ++c) {
            const int e0 = blk_base + c * CHUNK + t * 4;
            // 7 independent coalesced 16B loads
            float4 d4  = *(const float4*)(distances  + e0);
            float4 i4  = *(const float4*)(inv_d2_arr + e0);
            int4   p4  = *(const int4*)(pair_indices + e0);
            int4   se4 = *(const int4*)(src_elem + e0);
            int4   te4 = *(const int4*)(tgt_elem + e0);
            const float4* uvp = (const float4*)(uv + 3 * e0);   // 3*e0 % 4 == 0
            float4 u0 = uvp[0], u1 = uvp[1], u2 = uvp[2];

            float dd[4] = {d4.x, d4.y, d4.z, d4.w};
            float ii[4] = {i4.x, i4.y, i4.z, i4.w};
            int   pp[4] = {p4.x, p4.y, p4.z, p4.w};
            int   ss[4] = {se4.x, se4.y, se4.z, se4.w};
            int   tt[4] = {te4.x, te4.y, te4.z, te4.w};
            float ux[4] = {u0.x, u0.w, u1.z, u2.y};
            float uy[4] = {u0.y, u1.x, u1.w, u2.z};
            float uz[4] = {u0.z, u1.y, u2.x, u2.w};
            int sn[4] = {src4[c].x, src4[c].y, src4[c].z, src4[c].w};

            float tot[4];
#pragma unroll
            for (int k = 0; k < 4; ++k)
                tot[k] = edge_force(dd[k], ii[k], pp[k], ss[k], tt[k],
                                    s_AoR, s_invRho, s_C6, s_qq);

            int pos[4], bb[4], loc[4];
#pragma unroll
            for (int k = 0; k < 4; ++k) {
                bb[k]  = sn[k] >> NB_SHIFT;
                loc[k] = sn[k] & (NODES_PER_BUCKET - 1);
                pos[k] = s_base[bb[k]] + atomicAdd(&s_cnt[bb[k]], 1);
            }
#pragma unroll
            for (int k = 0; k < 4; ++k)
                if (pos[k] < cap)
                    buf[(size_t)bb[k] * cap + pos[k]] =
                        make_float4(-tot[k] * ux[k], -tot[k] * uy[k],
                                    -tot[k] * uz[k], __int_as_float(loc[k]));
        }
    } else {
        for (int j = 0; j < EDGES_PER_BLOCK / 256; ++j) {
            int e = blk_base + j * 256 + t;
            if (e >= n_edges) continue;
            float total = edge_force(distances[e], inv_d2_arr[e], pair_indices[e],
                                     src_elem[e], tgt_elem[e],
                                     s_AoR, s_invRho, s_C6, s_qq);
            float vx = uv[3 * e + 0], vy = uv[3 * e + 1], vz = uv[3 * e + 2];
            int node = edge_src[e];
            int b = node >> NB_SHIFT;
            int local = node & (NODES_PER_BUCKET - 1);
            int pos = s_base[b] + atomicAdd(&s_cnt[b], 1);
            if (pos < cap)
                buf[(size_t)b * cap + pos] =
                    make_float4(-total * vx, -total * vy, -total * vz,
                                __int_as_float(local));
        }
    }
}

// Phase B: one block per bucket; stream records coalesced with 2-way ILP,
// accumulate in LDS, write the bucket's 128 nodes coalesced.
__global__ __launch_bounds__(512) void gather_kernel(
    const float4* __restrict__ buf,
    const int*    __restrict__ g_cnt,
    float* __restrict__ forces,
    int cap, int n_out)
{
    __shared__ float s_acc[NODES_PER_BUCKET * 3];
    const int b = blockIdx.x;
    const int t = threadIdx.x;

    for (int k = t; k < NODES_PER_BUCKET * 3; k += 512) s_acc[k] = 0.0f;
    __syncthreads();

    int cnt = g_cnt[b];
    if (cnt > cap) cnt = cap;
    const float4* p = buf + (size_t)b * cap;

    int i = t;
    for (; i + 512 < cnt; i += 1024) {
        float4 r0 = p[i];
        float4 r1 = p[i + 512];
        int l0 = __float_as_int(r0.w);
        int l1 = __float_as_int(r1.w);
        atomicAdd(&s_acc[l0 * 3 + 0], r0.x);
        atomicAdd(&s_acc[l0 * 3 + 1], r0.y);
        atomicAdd(&s_acc[l0 * 3 + 2], r0.z);
        atomicAdd(&s_acc[l1 * 3 + 0], r1.x);
        atomicAdd(&s_acc[l1 * 3 + 1], r1.y);
        atomicAdd(&s_acc[l1 * 3 + 2], r1.z);
    }
    for (; i < cnt; i += 512) {
        float4 r = p[i];
        int l = __float_as_int(r.w);
        atomicAdd(&s_acc[l * 3 + 0], r.x);
        atomicAdd(&s_acc[l * 3 + 1], r.y);
        atomicAdd(&s_acc[l * 3 + 2], r.z);
    }
    __syncthreads();

    int base = b * NODES_PER_BUCKET * 3;
    for (int k = t; k < NODES_PER_BUCKET * 3; k += 512) {
        int o = base + k;
        if (o < n_out) forces[o] = s_acc[k];
    }
}

// Fallback: direct scatter with native fp32 atomics.
__global__ __launch_bounds__(256) void force_kernel_direct(
    const float* __restrict__ raw_charges,
    const float* __restrict__ A,
    const float* __restrict__ rho,
    const float* __restrict__ C,
    const float* __restrict__ distances,
    const float* __restrict__ inv_d2_arr,
    const float* __restrict__ uv,
    const int*   __restrict__ edge_src,
    const int*   __restrict__ pair_indices,
    const int*   __restrict__ src_elem,
    const int*   __restrict__ tgt_elem,
    float* __restrict__ forces,
    int n_edges)
{
    __shared__ float s_AoR[NUM_PAIRS], s_invRho[NUM_PAIRS], s_C6[NUM_PAIRS], s_qq[16];
    const int t = threadIdx.x;
    load_params(t, raw_charges, A, rho, C, s_AoR, s_invRho, s_C6, s_qq);
    __syncthreads();

    int e = blockIdx.x * blockDim.x + t;
    if (e >= n_edges) return;
    float total = edge_force(distances[e], inv_d2_arr[e], pair_indices[e],
                             src_elem[e], tgt_elem[e], s_AoR, s_invRho, s_C6, s_qq);
    float ux = uv[3 * e + 0], uy = uv[3 * e + 1], uz = uv[3 * e + 2];
    float* dst = forces + 3 * edge_src[e];
    unsafeAtomicAdd(dst + 0, -total * ux);
    unsafeAtomicAdd(dst + 1, -total * uy);
    unsafeAtomicAdd(dst + 2, -total * uz);
}

extern "C" void kernel_launch(void* const* d_in, const int* in_sizes, int n_in,
                              void* d_out, int out_size, void* d_ws, size_t ws_size,
                              hipStream_t stream) {
    const float* raw_charges = (const float*)d_in[0];
    const float* A           = (const float*)d_in[1];
    const float* rho         = (const float*)d_in[2];
    const float* C           = (const float*)d_in[3];
    const float* distances   = (const float*)d_in[4];
    const float* inv_d2      = (const float*)d_in[5];
    const float* uv          = (const float*)d_in[6];
    const int*   edge_index  = (const int*)d_in[7];   // [2, E]; row 0 = source
    const int*   pair_idx    = (const int*)d_in[8];
    const int*   src_elem    = (const int*)d_in[9];
    const int*   tgt_elem    = (const int*)d_in[10];

    float* forces = (float*)d_out;
    const int n_edges = in_sizes[4];
    const int n_out   = out_size;            // n_nodes * 3
    const int n_nodes = n_out / 3;

    const int B = 256;
    const int nb = (n_nodes + NODES_PER_BUCKET - 1) >> NB_SHIFT;
    const long mean = (long)n_edges / (nb > 0 ? nb : 1);
    int cap = (int)((mean + 10.0 * sqrt((double)mean) + 255.0));
    cap = (cap + 255) & ~255;

    const size_t hdr = 8192;   // g_cnt region
    const size_t need = hdr + (size_t)nb * (size_t)cap * sizeof(float4);

    if (nb <= MAX_NB && ws_size >= need) {
        int*    g_cnt = (int*)d_ws;
        float4* buf   = (float4*)((char*)d_ws + hdr);

        zero_int_kernel<<<(nb + B - 1) / B, B, 0, stream>>>(g_cnt, nb);

        int gridA = (n_edges + EDGES_PER_BLOCK - 1) / EDGES_PER_BLOCK;
        bin_kernel<<<gridA, B, 0, stream>>>(raw_charges, A, rho, C,
                                            distances, inv_d2, uv,
                                            edge_index, pair_idx, src_elem, tgt_elem,
                                            g_cnt, buf, cap, n_edges, nb);

        gather_kernel<<<nb, 512, 0, stream>>>(buf, g_cnt, forces, cap, n_out);
    } else {
        zero_kernel_f<<<(n_out + B - 1) / B, B, 0, stream>>>(forces, n_out);
        int grid = (n_edges + B - 1) / B;
        force_kernel_direct<<<grid, B, 0, stream>>>(raw_charges, A, rho, C,
                                                    distances, inv_d2, uv,
                                                    edge_index, pair_idx,
                                                    src_elem, tgt_elem,
                                                    forces, n_edges);
    }
}

// Round 6
// 436.741 us; speedup vs baseline: 2.5429x; 1.1425x over previous
//
#include <hip/hip_runtime.h>
#include <math.h>

#define NUM_PAIRS 10
#define BK_SHIFT 10                // 1024 nodes per bucket
#define BK_NODES 1024
#define MAX_BK 128
#define EPB 4096                   // edges per bin block
#define CHUNK 1024                 // staged edges per chunk (4 chunks/block)

__global__ void zero_int_kernel(int* __restrict__ p, int n) {
    int i = blockIdx.x * blockDim.x + threadIdx.x;
    if (i < n) p[i] = 0;
}

__global__ void zero_kernel_f(float* __restrict__ p, int n) {
    int i = blockIdx.x * blockDim.x + threadIdx.x;
    if (i < n) p[i] = 0.0f;
}

__device__ __forceinline__ void load_params(
    int t,
    const float* __restrict__ raw_charges,
    const float* __restrict__ A,
    const float* __restrict__ rho,
    const float* __restrict__ C,
    float* s_AoR, float* s_invRho, float* s_C6, float* s_qq)
{
    if (t < NUM_PAIRS) {
        float r = rho[t];
        float ir = 1.0f / r;
        s_invRho[t] = ir;
        s_AoR[t]    = A[t] * ir;
        s_C6[t]     = 6.0f * C[t];
    }
    if (t < 16) {
        float q0 = raw_charges[0];
        // charges: [Cd, Se, S, Zn] = [q0, -q0, raw[1], raw[2]]
        float qs0 = q0, qs1 = -q0, qs2 = raw_charges[1], qs3 = raw_charges[2];
        float qa = (t & 3) == 0 ? qs0 : (t & 3) == 1 ? qs1 : (t & 3) == 2 ? qs2 : qs3;
        int hb = t >> 2;
        float qb = hb == 0 ? qs0 : hb == 1 ? qs1 : hb == 2 ? qs2 : qs3;
        s_qq[t] = qa * qb;
    }
}

__device__ __forceinline__ float edge_force(
    float d, float inv_d2, int p, int se, int te,
    const float* s_AoR, const float* s_invRho, const float* s_C6, const float* s_qq)
{
    float inv_d  = inv_d2 * d;                 // 1/d without a division
    float inv_d6 = inv_d2 * inv_d2 * inv_d2;
    float pot  = s_AoR[p] * __expf(-d * s_invRho[p]) - s_C6[p] * inv_d6 * inv_d;
    float coul = s_qq[(te << 2) | se] * inv_d2;
    return pot + coul;
}

// Phase A: per-edge force vectors, block-level counting sort per 1024-edge
// chunk in LDS, copied out in bucket-order runs -> coalesced full-line writes.
__global__ __launch_bounds__(256) void bin_kernel(
    const float* __restrict__ raw_charges,
    const float* __restrict__ A,
    const float* __restrict__ rho,
    const float* __restrict__ C,
    const float* __restrict__ distances,
    const float* __restrict__ inv_d2_arr,
    const float* __restrict__ uv,            // [E,3]
    const int*   __restrict__ edge_src,
    const int*   __restrict__ pair_indices,
    const int*   __restrict__ src_elem,
    const int*   __restrict__ tgt_elem,
    int*            __restrict__ g_cnt,      // [nb]
    float*          __restrict__ buf3,       // [nb][cap][3]
    unsigned short* __restrict__ idx16,      // [nb][cap]
    int cap, int n_edges, int nb)
{
    __shared__ float s_AoR[NUM_PAIRS], s_invRho[NUM_PAIRS], s_C6[NUM_PAIRS], s_qq[16];
    __shared__ int hcnt[MAX_BK], hexcl[MAX_BK], hrun[MAX_BK], cursor[MAX_BK];
    __shared__ float s_fx[CHUNK], s_fy[CHUNK], s_fz[CHUNK];
    __shared__ int s_nd[CHUNK];

    const int t = threadIdx.x;
    load_params(t, raw_charges, A, rho, C, s_AoR, s_invRho, s_C6, s_qq);

    const int blk_base = blockIdx.x * EPB;
    const bool full = (blk_base + EPB) <= n_edges;

    if (full) {
        int4 src4[4];
#pragma unroll
        for (int c = 0; c < 4; ++c)
            src4[c] = *(const int4*)(edge_src + blk_base + c * CHUNK + t * 4);

        // block-level histogram -> one global reservation per (block,bucket)
        for (int k = t; k < nb; k += 256) cursor[k] = 0;
        __syncthreads();
#pragma unroll
        for (int c = 0; c < 4; ++c) {
            atomicAdd(&cursor[src4[c].x >> BK_SHIFT], 1);
            atomicAdd(&cursor[src4[c].y >> BK_SHIFT], 1);
            atomicAdd(&cursor[src4[c].z >> BK_SHIFT], 1);
            atomicAdd(&cursor[src4[c].w >> BK_SHIFT], 1);
        }
        __syncthreads();
        for (int k = t; k < nb; k += 256) {
            int c = cursor[k];
            cursor[k] = c ? atomicAdd(&g_cnt[k], c) : 0;   // now = global base
        }
        __syncthreads();

#pragma unroll
        for (int c = 0; c < 4; ++c) {
            const int e0 = blk_base + c * CHUNK + t * 4;
            // issue all chunk input loads up front (independent, coalesced 16B)
            float4 d4  = *(const float4*)(distances  + e0);
            float4 i4  = *(const float4*)(inv_d2_arr + e0);
            int4   p4  = *(const int4*)(pair_indices + e0);
            int4   se4 = *(const int4*)(src_elem + e0);
            int4   te4 = *(const int4*)(tgt_elem + e0);
            const float4* uvp = (const float4*)(uv + 3 * (size_t)e0);
            float4 u0 = uvp[0], u1 = uvp[1], u2 = uvp[2];

            int nd[4] = {src4[c].x, src4[c].y, src4[c].z, src4[c].w};

            // chunk histogram
            for (int k = t; k < nb; k += 256) { hcnt[k] = 0; hrun[k] = 0; }
            __syncthreads();
#pragma unroll
            for (int k = 0; k < 4; ++k) atomicAdd(&hcnt[nd[k] >> BK_SHIFT], 1);
            __syncthreads();

            // exclusive scan (Hillis-Steele, nb <= 128)
            if (t < nb) hexcl[t] = hcnt[t];
            __syncthreads();
            for (int off = 1; off < nb; off <<= 1) {
                int v = 0;
                if (t < nb && t >= off) v = hexcl[t - off];
                __syncthreads();
                if (t < nb && t >= off) hexcl[t] += v;
                __syncthreads();
            }
            if (t < nb) hexcl[t] -= hcnt[t];
            __syncthreads();

            // compute forces, claim staged slot, stage SoA
            float dd[4] = {d4.x, d4.y, d4.z, d4.w};
            float ii[4] = {i4.x, i4.y, i4.z, i4.w};
            int   pp[4] = {p4.x, p4.y, p4.z, p4.w};
            int   ss[4] = {se4.x, se4.y, se4.z, se4.w};
            int   tt[4] = {te4.x, te4.y, te4.z, te4.w};
            float ux[4] = {u0.x, u0.w, u1.z, u2.y};
            float uy[4] = {u0.y, u1.x, u1.w, u2.z};
            float uz[4] = {u0.z, u1.y, u2.x, u2.w};
#pragma unroll
            for (int k = 0; k < 4; ++k) {
                float tot = edge_force(dd[k], ii[k], pp[k], ss[k], tt[k],
                                       s_AoR, s_invRho, s_C6, s_qq);
                int bb  = nd[k] >> BK_SHIFT;
                int idx = hexcl[bb] + atomicAdd(&hrun[bb], 1);
                s_fx[idx] = -tot * ux[k];
                s_fy[idx] = -tot * uy[k];
                s_fz[idx] = -tot * uz[k];
                s_nd[idx] = nd[k];
            }
            __syncthreads();

            // copy out bucket-sorted -> coalesced runs in global
#pragma unroll
            for (int k = 0; k < CHUNK / 256; ++k) {
                int i = t + k * 256;
                int node = s_nd[i];
                int bb = node >> BK_SHIFT;
                int off = cursor[bb] + (i - hexcl[bb]);
                if (off < cap) {
                    size_t r = (size_t)bb * cap + off;
                    float* dst = buf3 + r * 3;
                    dst[0] = s_fx[i];
                    dst[1] = s_fy[i];
                    dst[2] = s_fz[i];
                    idx16[r] = (unsigned short)(node & (BK_NODES - 1));
                }
            }
            __syncthreads();
            if (t < nb) cursor[t] += hcnt[t];
            __syncthreads();
        }
    } else {
        // tail block (< EPB edges): simple per-edge path
        __syncthreads();
        for (int j = 0; j < EPB / 256; ++j) {
            int e = blk_base + j * 256 + t;
            if (e >= n_edges) continue;
            float total = edge_force(distances[e], inv_d2_arr[e], pair_indices[e],
                                     src_elem[e], tgt_elem[e],
                                     s_AoR, s_invRho, s_C6, s_qq);
            float vx = uv[3 * (size_t)e + 0], vy = uv[3 * (size_t)e + 1], vz = uv[3 * (size_t)e + 2];
            int node = edge_src[e];
            int bb = node >> BK_SHIFT;
            int pos = atomicAdd(&g_cnt[bb], 1);
            if (pos < cap) {
                size_t r = (size_t)bb * cap + pos;
                float* dst = buf3 + r * 3;
                dst[0] = -total * vx;
                dst[1] = -total * vy;
                dst[2] = -total * vz;
                idx16[r] = (unsigned short)(node & (BK_NODES - 1));
            }
        }
    }
}

// Phase B: grid (S, nb); block (s,b) accumulates a slice of bucket b's records
// into a 12KB LDS array (fire-and-forget ds_add_f32), writes partial.
__global__ __launch_bounds__(256) void gather_kernel(
    const float* __restrict__ buf3,
    const unsigned short* __restrict__ idx16,
    const int* __restrict__ g_cnt,
    float* __restrict__ part,        // [nb*S][BK_NODES*3]
    int cap)
{
    __shared__ float acc[BK_NODES * 3];
    const int s = blockIdx.x, S = gridDim.x, b = blockIdx.y;
    const int t = threadIdx.x;

    for (int k = t; k < BK_NODES * 3; k += 256) acc[k] = 0.0f;
    __syncthreads();

    int cnt = g_cnt[b];
    if (cnt > cap) cnt = cap;
    int lo = (int)((long)cnt * s / S);
    int hi = (int)((long)cnt * (s + 1) / S);

    const float* fp = buf3 + (size_t)b * cap * 3;
    const unsigned short* ip = idx16 + (size_t)b * cap;

#pragma unroll 2
    for (int i = lo + t; i < hi; i += 256) {
        int local = ip[i];
        float fx = fp[3 * (size_t)i + 0];
        float fy = fp[3 * (size_t)i + 1];
        float fz = fp[3 * (size_t)i + 2];
        atomicAdd(&acc[local * 3 + 0], fx);
        atomicAdd(&acc[local * 3 + 1], fy);
        atomicAdd(&acc[local * 3 + 2], fz);
    }
    __syncthreads();

    float* op = part + ((size_t)b * S + s) * (BK_NODES * 3);
    for (int k = t; k < BK_NODES * 3; k += 256) op[k] = acc[k];
}

__global__ __launch_bounds__(256) void reduce_kernel(
    const float* __restrict__ part, float* __restrict__ out, int n_out, int S)
{
    int i = blockIdx.x * blockDim.x + threadIdx.x;
    if (i >= n_out) return;
    int b = i / (BK_NODES * 3);
    int k = i - b * (BK_NODES * 3);
    const float* p = part + (size_t)b * S * (BK_NODES * 3) + k;
    float s = 0.0f;
    for (int j = 0; j < S; ++j) s += p[(size_t)j * (BK_NODES * 3)];
    out[i] = s;
}

// Fallback: direct scatter with native fp32 atomics.
__global__ __launch_bounds__(256) void force_kernel_direct(
    const float* __restrict__ raw_charges,
    const float* __restrict__ A,
    const float* __restrict__ rho,
    const float* __restrict__ C,
    const float* __restrict__ distances,
    const float* __restrict__ inv_d2_arr,
    const float* __restrict__ uv,
    const int*   __restrict__ edge_src,
    const int*   __restrict__ pair_indices,
    const int*   __restrict__ src_elem,
    const int*   __restrict__ tgt_elem,
    float* __restrict__ forces,
    int n_edges)
{
    __shared__ float s_AoR[NUM_PAIRS], s_invRho[NUM_PAIRS], s_C6[NUM_PAIRS], s_qq[16];
    const int t = threadIdx.x;
    load_params(t, raw_charges, A, rho, C, s_AoR, s_invRho, s_C6, s_qq);
    __syncthreads();

    int e = blockIdx.x * blockDim.x + t;
    if (e >= n_edges) return;
    float total = edge_force(distances[e], inv_d2_arr[e], pair_indices[e],
                             src_elem[e], tgt_elem[e], s_AoR, s_invRho, s_C6, s_qq);
    float ux = uv[3 * (size_t)e + 0], uy = uv[3 * (size_t)e + 1], uz = uv[3 * (size_t)e + 2];
    float* dst = forces + 3 * (size_t)edge_src[e];
    unsafeAtomicAdd(dst + 0, -total * ux);
    unsafeAtomicAdd(dst + 1, -total * uy);
    unsafeAtomicAdd(dst + 2, -total * uz);
}

extern "C" void kernel_launch(void* const* d_in, const int* in_sizes, int n_in,
                              void* d_out, int out_size, void* d_ws, size_t ws_size,
                              hipStream_t stream) {
    const float* raw_charges = (const float*)d_in[0];
    const float* A           = (const float*)d_in[1];
    const float* rho         = (const float*)d_in[2];
    const float* C           = (const float*)d_in[3];
    const float* distances   = (const float*)d_in[4];
    const float* inv_d2      = (const float*)d_in[5];
    const float* uv          = (const float*)d_in[6];
    const int*   edge_index  = (const int*)d_in[7];   // [2, E]; row 0 = source
    const int*   pair_idx    = (const int*)d_in[8];
    const int*   src_elem    = (const int*)d_in[9];
    const int*   tgt_elem    = (const int*)d_in[10];

    float* forces = (float*)d_out;
    const int n_edges = in_sizes[4];
    const int n_out   = out_size;            // n_nodes * 3
    const int n_nodes = n_out / 3;

    const int B = 256;
    const int nb = (n_nodes + BK_NODES - 1) >> BK_SHIFT;

    long meanb = ((long)n_edges * BK_NODES) / (n_nodes > 0 ? n_nodes : 1);
    int cap = (int)(meanb + 8.0 * sqrt((double)(meanb > 0 ? meanb : 1)) + 256.0);
    cap = (cap + 255) & ~255;

    const size_t hdr = 8192;
    size_t off_buf3 = hdr;
    size_t sz_buf3  = (size_t)nb * cap * 3 * sizeof(float);
    size_t off_idx  = (off_buf3 + sz_buf3 + 255) & ~(size_t)255;
    size_t sz_idx   = (size_t)nb * cap * sizeof(unsigned short);
    size_t off_part = (off_idx + sz_idx + 255) & ~(size_t)255;

    int S = 16;
    size_t need = off_part + (size_t)nb * S * (BK_NODES * 3) * sizeof(float);
    if (ws_size < need) { S = 8;  need = off_part + (size_t)nb * S * (BK_NODES * 3) * sizeof(float); }
    if (ws_size < need) { S = 4;  need = off_part + (size_t)nb * S * (BK_NODES * 3) * sizeof(float); }

    if (nb <= MAX_BK && ws_size >= need) {
        int*            g_cnt = (int*)d_ws;
        float*          buf3  = (float*)((char*)d_ws + off_buf3);
        unsigned short* idx16 = (unsigned short*)((char*)d_ws + off_idx);
        float*          part  = (float*)((char*)d_ws + off_part);

        zero_int_kernel<<<(nb + B - 1) / B, B, 0, stream>>>(g_cnt, nb);

        int gridA = (n_edges + EPB - 1) / EPB;
        bin_kernel<<<gridA, B, 0, stream>>>(raw_charges, A, rho, C,
                                            distances, inv_d2, uv,
                                            edge_index, pair_idx, src_elem, tgt_elem,
                                            g_cnt, buf3, idx16, cap, n_edges, nb);

        dim3 gridB(S, nb);
        gather_kernel<<<gridB, B, 0, stream>>>(buf3, idx16, g_cnt, part, cap);

        reduce_kernel<<<(n_out + B - 1) / B, B, 0, stream>>>(part, forces, n_out, S);
    } else {
        zero_kernel_f<<<(n_out + B - 1) / B, B, 0, stream>>>(forces, n_out);
        int grid = (n_edges + B - 1) / B;
        force_kernel_direct<<<grid, B, 0, stream>>>(raw_charges, A, rho, C,
                                                    distances, inv_d2, uv,
                                                    edge_index, pair_idx,
                                                    src_elem, tgt_elem,
                                                    forces, n_edges);
    }
}

// Round 7
// 405.945 us; speedup vs baseline: 2.7358x; 1.0759x over previous
//
#include <hip/hip_runtime.h>
#include <hip/hip_fp16.h>
#include <math.h>

#define NUM_PAIRS 10
#define BK_SHIFT 10                // 1024 nodes per bucket
#define BK_NODES 1024
#define MAX_BK 128
#define EPB 4096                   // edges per bin block, staged in one LDS pass
#define CHUNK 1024                 // compute-chunk (256 threads * 4 edges)

__global__ void zero_int_kernel(int* __restrict__ p, int n) {
    int i = blockIdx.x * blockDim.x + threadIdx.x;
    if (i < n) p[i] = 0;
}

__global__ void zero_kernel_f(float* __restrict__ p, int n) {
    int i = blockIdx.x * blockDim.x + threadIdx.x;
    if (i < n) p[i] = 0.0f;
}

__device__ __forceinline__ void load_params(
    int t,
    const float* __restrict__ raw_charges,
    const float* __restrict__ A,
    const float* __restrict__ rho,
    const float* __restrict__ C,
    float* s_AoR, float* s_invRho, float* s_C6, float* s_qq)
{
    if (t < NUM_PAIRS) {
        float r = rho[t];
        float ir = 1.0f / r;
        s_invRho[t] = ir;
        s_AoR[t]    = A[t] * ir;
        s_C6[t]     = 6.0f * C[t];
    }
    if (t < 16) {
        float q0 = raw_charges[0];
        // charges: [Cd, Se, S, Zn] = [q0, -q0, raw[1], raw[2]]
        float qs0 = q0, qs1 = -q0, qs2 = raw_charges[1], qs3 = raw_charges[2];
        float qa = (t & 3) == 0 ? qs0 : (t & 3) == 1 ? qs1 : (t & 3) == 2 ? qs2 : qs3;
        int hb = t >> 2;
        float qb = hb == 0 ? qs0 : hb == 1 ? qs1 : hb == 2 ? qs2 : qs3;
        s_qq[t] = qa * qb;
    }
}

__device__ __forceinline__ float edge_force(
    float d, float inv_d2, int p, int se, int te,
    const float* s_AoR, const float* s_invRho, const float* s_C6, const float* s_qq)
{
    float inv_d  = inv_d2 * d;                 // 1/d without a division
    float inv_d6 = inv_d2 * inv_d2 * inv_d2;
    float pot  = s_AoR[p] * __expf(-d * s_invRho[p]) - s_C6[p] * inv_d6 * inv_d;
    float coul = s_qq[(te << 2) | se] * inv_d2;
    return pot + coul;
}

// 8-byte record: fp16 fx,fy,fz + 10-bit bucket-local node index
__device__ __forceinline__ uint2 pack_rec(float fx, float fy, float fz, int local) {
    unsigned hx = (unsigned)__half_as_ushort(__float2half(fx));
    unsigned hy = (unsigned)__half_as_ushort(__float2half(fy));
    unsigned hz = (unsigned)__half_as_ushort(__float2half(fz));
    uint2 r;
    r.x = hx | (hy << 16);
    r.y = hz | ((unsigned)local << 16);
    return r;
}

// Phase A: single counting-sort pass per 4096-edge block; records staged in
// 32KB LDS, copied out in bucket-order coalesced runs (~42 recs * 8B each).
__global__ __launch_bounds__(256) void bin_kernel(
    const float* __restrict__ raw_charges,
    const float* __restrict__ A,
    const float* __restrict__ rho,
    const float* __restrict__ C,
    const float* __restrict__ distances,
    const float* __restrict__ uv,            // [E,3]
    const int*   __restrict__ edge_src,
    const int*   __restrict__ pair_indices,
    const int*   __restrict__ src_elem,
    const int*   __restrict__ tgt_elem,
    int*   __restrict__ g_cnt,               // [nb]
    uint2* __restrict__ buf,                 // [nb][cap]
    int cap, int n_edges, int nb)
{
    __shared__ float s_AoR[NUM_PAIRS], s_invRho[NUM_PAIRS], s_C6[NUM_PAIRS], s_qq[16];
    __shared__ int hcnt[MAX_BK], hexcl[MAX_BK], gbase[MAX_BK], hrun[MAX_BK];
    __shared__ int s_wsum[2];
    __shared__ uint2 s_rec[EPB];             // 32 KB
    __shared__ unsigned char s_bb[EPB];      // 4 KB

    const int t = threadIdx.x;
    load_params(t, raw_charges, A, rho, C, s_AoR, s_invRho, s_C6, s_qq);
    for (int k = t; k < nb; k += 256) { hcnt[k] = 0; hrun[k] = 0; }
    __syncthreads();

    const int blk_base = blockIdx.x * EPB;
    const bool full = (blk_base + EPB) <= n_edges;

    if (full) {
        int4 src4[4];
#pragma unroll
        for (int c = 0; c < 4; ++c)
            src4[c] = *(const int4*)(edge_src + blk_base + c * CHUNK + t * 4);
#pragma unroll
        for (int c = 0; c < 4; ++c) {
            atomicAdd(&hcnt[src4[c].x >> BK_SHIFT], 1);
            atomicAdd(&hcnt[src4[c].y >> BK_SHIFT], 1);
            atomicAdd(&hcnt[src4[c].z >> BK_SHIFT], 1);
            atomicAdd(&hcnt[src4[c].w >> BK_SHIFT], 1);
        }
        __syncthreads();

        // 2-wave shfl exclusive scan (nb <= 128) + global reservation
        {
            const int w = t >> 6, lane = t & 63;
            int v = 0, sum = 0;
            if (t < 128) {
                v = (t < nb) ? hcnt[t] : 0;
                sum = v;
#pragma unroll
                for (int off = 1; off < 64; off <<= 1) {
                    int u = __shfl_up(sum, off, 64);
                    if (lane >= off) sum += u;
                }
                if (lane == 63) s_wsum[w] = sum;
            }
            __syncthreads();
            if (t < nb) {
                hexcl[t] = sum - v + (w ? s_wsum[0] : 0);
                gbase[t] = v ? atomicAdd(&g_cnt[t], v) : 0;
            }
            __syncthreads();
        }

        // compute 16 edges/thread in 4 chunks; claim sorted LDS slot; stage
#pragma unroll
        for (int c = 0; c < 4; ++c) {
            const int e0 = blk_base + c * CHUNK + t * 4;
            float4 d4  = *(const float4*)(distances + e0);
            int4   p4  = *(const int4*)(pair_indices + e0);
            int4   se4 = *(const int4*)(src_elem + e0);
            int4   te4 = *(const int4*)(tgt_elem + e0);
            const float4* uvp = (const float4*)(uv + 3 * (size_t)e0);
            float4 u0 = uvp[0], u1 = uvp[1], u2 = uvp[2];

            float dd[4] = {d4.x, d4.y, d4.z, d4.w};
            int   pp[4] = {p4.x, p4.y, p4.z, p4.w};
            int   ss[4] = {se4.x, se4.y, se4.z, se4.w};
            int   tt[4] = {te4.x, te4.y, te4.z, te4.w};
            float ux[4] = {u0.x, u0.w, u1.z, u2.y};
            float uy[4] = {u0.y, u1.x, u1.w, u2.z};
            float uz[4] = {u0.z, u1.y, u2.x, u2.w};
            int   nd[4] = {src4[c].x, src4[c].y, src4[c].z, src4[c].w};

#pragma unroll
            for (int k = 0; k < 4; ++k) {
                float d = dd[k];
                float inv_d2 = 1.0f / (d * d);   // replaces the 25.6MB input read
                float tot = edge_force(d, inv_d2, pp[k], ss[k], tt[k],
                                       s_AoR, s_invRho, s_C6, s_qq);
                int bb  = nd[k] >> BK_SHIFT;
                int idx = hexcl[bb] + atomicAdd(&hrun[bb], 1);
                s_rec[idx] = pack_rec(-tot * ux[k], -tot * uy[k], -tot * uz[k],
                                      nd[k] & (BK_NODES - 1));
                s_bb[idx] = (unsigned char)bb;
            }
        }
        __syncthreads();

        // copy out bucket-sorted -> coalesced runs in global
#pragma unroll
        for (int k = 0; k < EPB / 256; ++k) {
            int i = t + k * 256;
            int bb = s_bb[i];
            int off = gbase[bb] + (i - hexcl[bb]);
            if (off < cap) buf[(size_t)bb * cap + off] = s_rec[i];
        }
    } else {
        // tail block: per-edge direct append
        for (int j = 0; j < EPB / 256; ++j) {
            int e = blk_base + j * 256 + t;
            if (e >= n_edges) continue;
            float d = distances[e];
            float inv_d2 = 1.0f / (d * d);
            float total = edge_force(d, inv_d2, pair_indices[e],
                                     src_elem[e], tgt_elem[e],
                                     s_AoR, s_invRho, s_C6, s_qq);
            float vx = uv[3 * (size_t)e + 0];
            float vy = uv[3 * (size_t)e + 1];
            float vz = uv[3 * (size_t)e + 2];
            int node = edge_src[e];
            int bb = node >> BK_SHIFT;
            int pos = atomicAdd(&g_cnt[bb], 1);
            if (pos < cap)
                buf[(size_t)bb * cap + pos] =
                    pack_rec(-total * vx, -total * vy, -total * vz,
                             node & (BK_NODES - 1));
        }
    }
}

// Phase B: grid (S, nb); block (s,b) accumulates its slice of bucket b into
// a 12KB LDS array (fp32 LDS atomics), writes a partial.
__global__ __launch_bounds__(256) void gather_kernel(
    const uint2* __restrict__ buf,
    const int*   __restrict__ g_cnt,
    float* __restrict__ part,        // [nb*S][BK_NODES*3]
    int cap)
{
    __shared__ float acc[BK_NODES * 3];
    const int s = blockIdx.x, S = gridDim.x, b = blockIdx.y;
    const int t = threadIdx.x;

    for (int k = t; k < BK_NODES * 3; k += 256) acc[k] = 0.0f;
    __syncthreads();

    int cnt = g_cnt[b];
    if (cnt > cap) cnt = cap;
    int lo = (int)((long)cnt * s / S);
    int hi = (int)((long)cnt * (s + 1) / S);

    const uint2* p = buf + (size_t)b * cap;

#pragma unroll 2
    for (int i = lo + t; i < hi; i += 256) {
        uint2 r = p[i];
        float fx = __half2float(__ushort_as_half((unsigned short)(r.x & 0xffff)));
        float fy = __half2float(__ushort_as_half((unsigned short)(r.x >> 16)));
        float fz = __half2float(__ushort_as_half((unsigned short)(r.y & 0xffff)));
        int local = (int)(r.y >> 16);
        atomicAdd(&acc[local * 3 + 0], fx);
        atomicAdd(&acc[local * 3 + 1], fy);
        atomicAdd(&acc[local * 3 + 2], fz);
    }
    __syncthreads();

    float* op = part + ((size_t)b * S + s) * (BK_NODES * 3);
    for (int k = t; k < BK_NODES * 3; k += 256) op[k] = acc[k];
}

// part layout in float4: [nb][S][768]; out float4 i belongs to bucket i/768.
__global__ __launch_bounds__(256) void reduce_kernel(
    const float4* __restrict__ part, float4* __restrict__ out, int n4, int S)
{
    int i = blockIdx.x * blockDim.x + threadIdx.x;
    if (i >= n4) return;
    int b = i / 768;
    int k = i - b * 768;
    const float4* p = part + (size_t)b * S * 768 + k;
    float4 s = make_float4(0.f, 0.f, 0.f, 0.f);
    for (int j = 0; j < S; ++j) {
        float4 v = p[(size_t)j * 768];
        s.x += v.x; s.y += v.y; s.z += v.z; s.w += v.w;
    }
    out[i] = s;
}

// Fallback: direct scatter with native fp32 atomics.
__global__ __launch_bounds__(256) void force_kernel_direct(
    const float* __restrict__ raw_charges,
    const float* __restrict__ A,
    const float* __restrict__ rho,
    const float* __restrict__ C,
    const float* __restrict__ distances,
    const float* __restrict__ uv,
    const int*   __restrict__ edge_src,
    const int*   __restrict__ pair_indices,
    const int*   __restrict__ src_elem,
    const int*   __restrict__ tgt_elem,
    float* __restrict__ forces,
    int n_edges)
{
    __shared__ float s_AoR[NUM_PAIRS], s_invRho[NUM_PAIRS], s_C6[NUM_PAIRS], s_qq[16];
    const int t = threadIdx.x;
    load_params(t, raw_charges, A, rho, C, s_AoR, s_invRho, s_C6, s_qq);
    __syncthreads();

    int e = blockIdx.x * blockDim.x + t;
    if (e >= n_edges) return;
    float d = distances[e];
    float inv_d2 = 1.0f / (d * d);
    float total = edge_force(d, inv_d2, pair_indices[e],
                             src_elem[e], tgt_elem[e], s_AoR, s_invRho, s_C6, s_qq);
    float ux = uv[3 * (size_t)e + 0], uy = uv[3 * (size_t)e + 1], uz = uv[3 * (size_t)e + 2];
    float* dst = forces + 3 * (size_t)edge_src[e];
    unsafeAtomicAdd(dst + 0, -total * ux);
    unsafeAtomicAdd(dst + 1, -total * uy);
    unsafeAtomicAdd(dst + 2, -total * uz);
}

extern "C" void kernel_launch(void* const* d_in, const int* in_sizes, int n_in,
                              void* d_out, int out_size, void* d_ws, size_t ws_size,
                              hipStream_t stream) {
    const float* raw_charges = (const float*)d_in[0];
    const float* A           = (const float*)d_in[1];
    const float* rho         = (const float*)d_in[2];
    const float* C           = (const float*)d_in[3];
    const float* distances   = (const float*)d_in[4];
    // d_in[5] (inverse_distances_sq) recomputed on the fly
    const float* uv          = (const float*)d_in[6];
    const int*   edge_index  = (const int*)d_in[7];   // [2, E]; row 0 = source
    const int*   pair_idx    = (const int*)d_in[8];
    const int*   src_elem    = (const int*)d_in[9];
    const int*   tgt_elem    = (const int*)d_in[10];

    float* forces = (float*)d_out;
    const int n_edges = in_sizes[4];
    const int n_out   = out_size;            // n_nodes * 3
    const int n_nodes = n_out / 3;

    const int B = 256;
    const int nb = (n_nodes + BK_NODES - 1) >> BK_SHIFT;

    long meanb = ((long)n_edges * BK_NODES) / (n_nodes > 0 ? n_nodes : 1);
    int cap = (int)(meanb + 8.0 * sqrt((double)(meanb > 0 ? meanb : 1)) + 256.0);
    cap = (cap + 255) & ~255;

    const size_t hdr = 8192;
    size_t off_buf = hdr;
    size_t sz_buf  = (size_t)nb * cap * sizeof(uint2);
    size_t off_part = (off_buf + sz_buf + 255) & ~(size_t)255;

    int S = 8;
    size_t need = off_part + (size_t)nb * S * (BK_NODES * 3) * sizeof(float);
    if (ws_size < need) { S = 4; need = off_part + (size_t)nb * S * (BK_NODES * 3) * sizeof(float); }
    if (ws_size < need) { S = 2; need = off_part + (size_t)nb * S * (BK_NODES * 3) * sizeof(float); }

    if (nb <= MAX_BK && ws_size >= need && (n_out % 4) == 0) {
        int*   g_cnt = (int*)d_ws;
        uint2* buf   = (uint2*)((char*)d_ws + off_buf);
        float* part  = (float*)((char*)d_ws + off_part);

        zero_int_kernel<<<(nb + B - 1) / B, B, 0, stream>>>(g_cnt, nb);

        int gridA = (n_edges + EPB - 1) / EPB;
        bin_kernel<<<gridA, B, 0, stream>>>(raw_charges, A, rho, C,
                                            distances, uv,
                                            edge_index, pair_idx, src_elem, tgt_elem,
                                            g_cnt, buf, cap, n_edges, nb);

        dim3 gridB(S, nb);
        gather_kernel<<<gridB, B, 0, stream>>>(buf, g_cnt, part, cap);

        int n4 = n_out / 4;
        reduce_kernel<<<(n4 + B - 1) / B, B, 0, stream>>>((const float4*)part,
                                                          (float4*)forces, n4, S);
    } else {
        zero_kernel_f<<<(n_out + B - 1) / B, B, 0, stream>>>(forces, n_out);
        int grid = (n_edges + B - 1) / B;
        force_kernel_direct<<<grid, B, 0, stream>>>(raw_charges, A, rho, C,
                                                    distances, uv,
                                                    edge_index, pair_idx,
                                                    src_elem, tgt_elem,
                                                    forces, n_edges);
    }
}

// Round 8
// 395.126 us; speedup vs baseline: 2.8107x; 1.0274x over previous
//
#include <hip/hip_runtime.h>
#include <hip/hip_fp16.h>
#include <math.h>

#define NUM_PAIRS 10
#define BK_SHIFT 10                // 1024 nodes per bucket
#define BK_NODES 1024
#define MAX_BK 128
#define EPB 4096                   // edges per bin block, staged in one LDS pass
#define CHUNK 1024                 // compute-chunk (256 threads * 4 edges)

__global__ void zero_int_kernel(int* __restrict__ p, int n) {
    int i = blockIdx.x * blockDim.x + threadIdx.x;
    if (i < n) p[i] = 0;
}

__global__ void zero_kernel_f(float* __restrict__ p, int n) {
    int i = blockIdx.x * blockDim.x + threadIdx.x;
    if (i < n) p[i] = 0.0f;
}

__device__ __forceinline__ void load_params(
    int t,
    const float* __restrict__ raw_charges,
    const float* __restrict__ A,
    const float* __restrict__ rho,
    const float* __restrict__ C,
    float* s_AoR, float* s_invRho, float* s_C6, float* s_qq)
{
    if (t < NUM_PAIRS) {
        float r = rho[t];
        float ir = 1.0f / r;
        s_invRho[t] = ir;
        s_AoR[t]    = A[t] * ir;
        s_C6[t]     = 6.0f * C[t];
    }
    if (t < 16) {
        float q0 = raw_charges[0];
        // charges: [Cd, Se, S, Zn] = [q0, -q0, raw[1], raw[2]]
        float qs0 = q0, qs1 = -q0, qs2 = raw_charges[1], qs3 = raw_charges[2];
        float qa = (t & 3) == 0 ? qs0 : (t & 3) == 1 ? qs1 : (t & 3) == 2 ? qs2 : qs3;
        int hb = t >> 2;
        float qb = hb == 0 ? qs0 : hb == 1 ? qs1 : hb == 2 ? qs2 : qs3;
        s_qq[t] = qa * qb;
    }
}

__device__ __forceinline__ float edge_force(
    float d, float inv_d2, int p, int se, int te,
    const float* s_AoR, const float* s_invRho, const float* s_C6, const float* s_qq)
{
    float inv_d  = inv_d2 * d;                 // 1/d without a division
    float inv_d6 = inv_d2 * inv_d2 * inv_d2;
    float pot  = s_AoR[p] * __expf(-d * s_invRho[p]) - s_C6[p] * inv_d6 * inv_d;
    float coul = s_qq[(te << 2) | se] * inv_d2;
    return pot + coul;
}

// 8-byte record: fp16 fx,fy,fz + 10-bit bucket-local node index
__device__ __forceinline__ uint2 pack_rec(float fx, float fy, float fz, int local) {
    unsigned hx = (unsigned)__half_as_ushort(__float2half(fx));
    unsigned hy = (unsigned)__half_as_ushort(__float2half(fy));
    unsigned hz = (unsigned)__half_as_ushort(__float2half(fz));
    uint2 r;
    r.x = hx | (hy << 16);
    r.y = hz | ((unsigned)local << 16);
    return r;
}

// Phase A: single counting-sort pass per 4096-edge block; records staged in
// 32KB LDS, copied out in bucket-order coalesced runs.
__global__ __launch_bounds__(256) void bin_kernel(
    const float* __restrict__ raw_charges,
    const float* __restrict__ A,
    const float* __restrict__ rho,
    const float* __restrict__ C,
    const float* __restrict__ distances,
    const float* __restrict__ uv,            // [E,3]
    const int*   __restrict__ edge_src,
    const int*   __restrict__ pair_indices,
    const int*   __restrict__ src_elem,
    const int*   __restrict__ tgt_elem,
    int*   __restrict__ g_cnt,               // [nb]
    uint2* __restrict__ buf,                 // [nb][cap]
    int cap, int n_edges, int nb)
{
    __shared__ float s_AoR[NUM_PAIRS], s_invRho[NUM_PAIRS], s_C6[NUM_PAIRS], s_qq[16];
    __shared__ int hcnt[MAX_BK], hexcl[MAX_BK], gbase[MAX_BK], hrun[MAX_BK];
    __shared__ int s_wsum[2];
    __shared__ uint2 s_rec[EPB];             // 32 KB
    __shared__ unsigned char s_bb[EPB];      // 4 KB

    const int t = threadIdx.x;
    load_params(t, raw_charges, A, rho, C, s_AoR, s_invRho, s_C6, s_qq);
    for (int k = t; k < nb; k += 256) { hcnt[k] = 0; hrun[k] = 0; }
    __syncthreads();

    const int blk_base = blockIdx.x * EPB;
    const bool full = (blk_base + EPB) <= n_edges;

    if (full) {
        int4 src4[4];
#pragma unroll
        for (int c = 0; c < 4; ++c)
            src4[c] = *(const int4*)(edge_src + blk_base + c * CHUNK + t * 4);
#pragma unroll
        for (int c = 0; c < 4; ++c) {
            atomicAdd(&hcnt[src4[c].x >> BK_SHIFT], 1);
            atomicAdd(&hcnt[src4[c].y >> BK_SHIFT], 1);
            atomicAdd(&hcnt[src4[c].z >> BK_SHIFT], 1);
            atomicAdd(&hcnt[src4[c].w >> BK_SHIFT], 1);
        }
        __syncthreads();

        // 2-wave shfl exclusive scan (nb <= 128) + global reservation
        {
            const int w = t >> 6, lane = t & 63;
            int v = 0, sum = 0;
            if (t < 128) {
                v = (t < nb) ? hcnt[t] : 0;
                sum = v;
#pragma unroll
                for (int off = 1; off < 64; off <<= 1) {
                    int u = __shfl_up(sum, off, 64);
                    if (lane >= off) sum += u;
                }
                if (lane == 63) s_wsum[w] = sum;
            }
            __syncthreads();
            if (t < nb) {
                hexcl[t] = sum - v + (w ? s_wsum[0] : 0);
                gbase[t] = v ? atomicAdd(&g_cnt[t], v) : 0;
            }
            __syncthreads();
        }

        // compute 16 edges/thread in 4 chunks; claim sorted LDS slot; stage
#pragma unroll
        for (int c = 0; c < 4; ++c) {
            const int e0 = blk_base + c * CHUNK + t * 4;
            float4 d4  = *(const float4*)(distances + e0);
            int4   p4  = *(const int4*)(pair_indices + e0);
            int4   se4 = *(const int4*)(src_elem + e0);
            int4   te4 = *(const int4*)(tgt_elem + e0);
            const float4* uvp = (const float4*)(uv + 3 * (size_t)e0);
            float4 u0 = uvp[0], u1 = uvp[1], u2 = uvp[2];

            float dd[4] = {d4.x, d4.y, d4.z, d4.w};
            int   pp[4] = {p4.x, p4.y, p4.z, p4.w};
            int   ss[4] = {se4.x, se4.y, se4.z, se4.w};
            int   tt[4] = {te4.x, te4.y, te4.z, te4.w};
            float ux[4] = {u0.x, u0.w, u1.z, u2.y};
            float uy[4] = {u0.y, u1.x, u1.w, u2.z};
            float uz[4] = {u0.z, u1.y, u2.x, u2.w};
            int   nd[4] = {src4[c].x, src4[c].y, src4[c].z, src4[c].w};

#pragma unroll
            for (int k = 0; k < 4; ++k) {
                float d = dd[k];
                float inv_d2 = 1.0f / (d * d);
                float tot = edge_force(d, inv_d2, pp[k], ss[k], tt[k],
                                       s_AoR, s_invRho, s_C6, s_qq);
                int bb  = nd[k] >> BK_SHIFT;
                int idx = hexcl[bb] + atomicAdd(&hrun[bb], 1);
                s_rec[idx] = pack_rec(-tot * ux[k], -tot * uy[k], -tot * uz[k],
                                      nd[k] & (BK_NODES - 1));
                s_bb[idx] = (unsigned char)bb;
            }
        }
        __syncthreads();

        // copy out bucket-sorted -> coalesced runs in global
#pragma unroll
        for (int k = 0; k < EPB / 256; ++k) {
            int i = t + k * 256;
            int bb = s_bb[i];
            int off = gbase[bb] + (i - hexcl[bb]);
            if (off < cap) buf[(size_t)bb * cap + off] = s_rec[i];
        }
    } else {
        // tail block: per-edge direct append
        for (int j = 0; j < EPB / 256; ++j) {
            int e = blk_base + j * 256 + t;
            if (e >= n_edges) continue;
            float d = distances[e];
            float inv_d2 = 1.0f / (d * d);
            float total = edge_force(d, inv_d2, pair_indices[e],
                                     src_elem[e], tgt_elem[e],
                                     s_AoR, s_invRho, s_C6, s_qq);
            float vx = uv[3 * (size_t)e + 0];
            float vy = uv[3 * (size_t)e + 1];
            float vz = uv[3 * (size_t)e + 2];
            int node = edge_src[e];
            int bb = node >> BK_SHIFT;
            int pos = atomicAdd(&g_cnt[bb], 1);
            if (pos < cap)
                buf[(size_t)bb * cap + pos] =
                    pack_rec(-total * vx, -total * vy, -total * vz,
                             node & (BK_NODES - 1));
        }
    }
}

__device__ __forceinline__ void acc_rec(float* acc, uint2 r) {
    float fx = __half2float(__ushort_as_half((unsigned short)(r.x & 0xffff)));
    float fy = __half2float(__ushort_as_half((unsigned short)(r.x >> 16)));
    float fz = __half2float(__ushort_as_half((unsigned short)(r.y & 0xffff)));
    int local = (int)(r.y >> 16);
    // unsafeAtomicAdd -> native ds_add_f32 (no return, no CAS loop)
    unsafeAtomicAdd(&acc[local * 3 + 0], fx);
    unsafeAtomicAdd(&acc[local * 3 + 1], fy);
    unsafeAtomicAdd(&acc[local * 3 + 2], fz);
}

// Phase B: grid (S, nb); block (s,b) accumulates its slice of bucket b into
// a 12KB LDS array (native ds_add_f32), writes a partial.
__global__ __launch_bounds__(256) void gather_kernel(
    const uint2* __restrict__ buf,
    const int*   __restrict__ g_cnt,
    float* __restrict__ part,        // [nb*S][BK_NODES*3]
    int cap)
{
    __shared__ float acc[BK_NODES * 3];
    const int s = blockIdx.x, S = gridDim.x, b = blockIdx.y;
    const int t = threadIdx.x;

    for (int k = t; k < BK_NODES * 3; k += 256) acc[k] = 0.0f;
    __syncthreads();

    int cnt = g_cnt[b];
    if (cnt > cap) cnt = cap;
    int lo = (int)((long)cnt * s / S);
    int hi = (int)((long)cnt * (s + 1) / S);

    const uint2* p = buf + (size_t)b * cap;

    int i = lo + t;
    // 4-batch: 4 independent loads in flight, then 12 independent ds_adds
    for (; i + 768 < hi; i += 1024) {
        uint2 r0 = p[i];
        uint2 r1 = p[i + 256];
        uint2 r2 = p[i + 512];
        uint2 r3 = p[i + 768];
        acc_rec(acc, r0);
        acc_rec(acc, r1);
        acc_rec(acc, r2);
        acc_rec(acc, r3);
    }
    for (; i < hi; i += 256) acc_rec(acc, p[i]);
    __syncthreads();

    float* op = part + ((size_t)b * S + s) * (BK_NODES * 3);
    for (int k = t; k < BK_NODES * 3; k += 256) op[k] = acc[k];
}

// part layout in float4: [nb][S][768]; out float4 i belongs to bucket i/768.
__global__ __launch_bounds__(256) void reduce_kernel(
    const float4* __restrict__ part, float4* __restrict__ out, int n4, int S)
{
    int i = blockIdx.x * blockDim.x + threadIdx.x;
    if (i >= n4) return;
    int b = i / 768;
    int k = i - b * 768;
    const float4* p = part + (size_t)b * S * 768 + k;
    float4 s = make_float4(0.f, 0.f, 0.f, 0.f);
    for (int j = 0; j < S; ++j) {
        float4 v = p[(size_t)j * 768];
        s.x += v.x; s.y += v.y; s.z += v.z; s.w += v.w;
    }
    out[i] = s;
}

// Fallback: direct scatter with native fp32 atomics.
__global__ __launch_bounds__(256) void force_kernel_direct(
    const float* __restrict__ raw_charges,
    const float* __restrict__ A,
    const float* __restrict__ rho,
    const float* __restrict__ C,
    const float* __restrict__ distances,
    const float* __restrict__ uv,
    const int*   __restrict__ edge_src,
    const int*   __restrict__ pair_indices,
    const int*   __restrict__ src_elem,
    const int*   __restrict__ tgt_elem,
    float* __restrict__ forces,
    int n_edges)
{
    __shared__ float s_AoR[NUM_PAIRS], s_invRho[NUM_PAIRS], s_C6[NUM_PAIRS], s_qq[16];
    const int t = threadIdx.x;
    load_params(t, raw_charges, A, rho, C, s_AoR, s_invRho, s_C6, s_qq);
    __syncthreads();

    int e = blockIdx.x * blockDim.x + t;
    if (e >= n_edges) return;
    float d = distances[e];
    float inv_d2 = 1.0f / (d * d);
    float total = edge_force(d, inv_d2, pair_indices[e],
                             src_elem[e], tgt_elem[e], s_AoR, s_invRho, s_C6, s_qq);
    float ux = uv[3 * (size_t)e + 0], uy = uv[3 * (size_t)e + 1], uz = uv[3 * (size_t)e + 2];
    float* dst = forces + 3 * (size_t)edge_src[e];
    unsafeAtomicAdd(dst + 0, -total * ux);
    unsafeAtomicAdd(dst + 1, -total * uy);
    unsafeAtomicAdd(dst + 2, -total * uz);
}

extern "C" void kernel_launch(void* const* d_in, const int* in_sizes, int n_in,
                              void* d_out, int out_size, void* d_ws, size_t ws_size,
                              hipStream_t stream) {
    const float* raw_charges = (const float*)d_in[0];
    const float* A           = (const float*)d_in[1];
    const float* rho         = (const float*)d_in[2];
    const float* C           = (const float*)d_in[3];
    const float* distances   = (const float*)d_in[4];
    // d_in[5] (inverse_distances_sq) recomputed on the fly
    const float* uv          = (const float*)d_in[6];
    const int*   edge_index  = (const int*)d_in[7];   // [2, E]; row 0 = source
    const int*   pair_idx    = (const int*)d_in[8];
    const int*   src_elem    = (const int*)d_in[9];
    const int*   tgt_elem    = (const int*)d_in[10];

    float* forces = (float*)d_out;
    const int n_edges = in_sizes[4];
    const int n_out   = out_size;            // n_nodes * 3
    const int n_nodes = n_out / 3;

    const int B = 256;
    const int nb = (n_nodes + BK_NODES - 1) >> BK_SHIFT;

    long meanb = ((long)n_edges * BK_NODES) / (n_nodes > 0 ? n_nodes : 1);
    int cap = (int)(meanb + 8.0 * sqrt((double)(meanb > 0 ? meanb : 1)) + 256.0);
    cap = (cap + 255) & ~255;

    const size_t hdr = 8192;
    size_t off_buf = hdr;
    size_t sz_buf  = (size_t)nb * cap * sizeof(uint2);
    size_t off_part = (off_buf + sz_buf + 255) & ~(size_t)255;

    int S = 16;
    size_t need = off_part + (size_t)nb * S * (BK_NODES * 3) * sizeof(float);
    if (ws_size < need) { S = 8; need = off_part + (size_t)nb * S * (BK_NODES * 3) * sizeof(float); }
    if (ws_size < need) { S = 4; need = off_part + (size_t)nb * S * (BK_NODES * 3) * sizeof(float); }
    if (ws_size < need) { S = 2; need = off_part + (size_t)nb * S * (BK_NODES * 3) * sizeof(float); }

    if (nb <= MAX_BK && ws_size >= need && (n_out % 4) == 0) {
        int*   g_cnt = (int*)d_ws;
        uint2* buf   = (uint2*)((char*)d_ws + off_buf);
        float* part  = (float*)((char*)d_ws + off_part);

        zero_int_kernel<<<(nb + B - 1) / B, B, 0, stream>>>(g_cnt, nb);

        int gridA = (n_edges + EPB - 1) / EPB;
        bin_kernel<<<gridA, B, 0, stream>>>(raw_charges, A, rho, C,
                                            distances, uv,
                                            edge_index, pair_idx, src_elem, tgt_elem,
                                            g_cnt, buf, cap, n_edges, nb);

        dim3 gridB(S, nb);
        gather_kernel<<<gridB, B, 0, stream>>>(buf, g_cnt, part, cap);

        int n4 = n_out / 4;
        reduce_kernel<<<(n4 + B - 1) / B, B, 0, stream>>>((const float4*)part,
                                                          (float4*)forces, n4, S);
    } else {
        zero_kernel_f<<<(n_out + B - 1) / B, B, 0, stream>>>(forces, n_out);
        int grid = (n_edges + B - 1) / B;
        force_kernel_direct<<<grid, B, 0, stream>>>(raw_charges, A, rho, C,
                                                    distances, uv,
                                                    edge_index, pair_idx,
                                                    src_elem, tgt_elem,
                                                    forces, n_edges);
    }
}